// Round 1
// 478.426 us; speedup vs baseline: 1.1767x; 1.1767x over previous
//
#include <hip/hip_runtime.h>
#include <stdint.h>

typedef int i32x4 __attribute__((ext_vector_type(4)));
typedef int8_t s8;

// ---- async global->LDS, 16B per lane ----
__device__ __forceinline__ void gload_lds16(const void* g, uint32_t lds_addr) {
  __builtin_amdgcn_global_load_lds(
      (const __attribute__((address_space(1))) void*)(uintptr_t)g,
      (__attribute__((address_space(3))) void*)(uintptr_t)lds_addr,
      16, 0, 0);
}

// ---- 2-level int8 split: x ~= s*(q1 + q2/128), |err| <= s/512 ----
__device__ __forceinline__ void qsplit(float x, float s, float sinv, float s2inv,
                                       int& q1, int& q2) {
  float a = rintf(x * sinv);
  a = fminf(fmaxf(a, -127.f), 127.f);
  float r = fmaf(a, -s, x);
  float b = fminf(fmaxf(rintf(r * s2inv), -127.f), 127.f);
  q1 = (int)a; q2 = (int)b;
}
__device__ __forceinline__ uint32_t pack4(int b0, int b1, int b2, int b3) {
  return ((uint32_t)(uint8_t)b0) | ((uint32_t)(uint8_t)b1 << 8) |
         ((uint32_t)(uint8_t)b2 << 16) | ((uint32_t)(uint8_t)b3 << 24);
}

#define SQ (8.0f / 127.0f)
#define SQ_INV 15.875f
#define SQ2_INV 2032.0f

// ---- Q: fp32 -> q1,q2 int8; 8 elems/thread ----
__global__ __launch_bounds__(256) void cvt_q_i8(const float* __restrict__ x,
                                                s8* __restrict__ a, s8* __restrict__ b) {
  size_t i = ((size_t)blockIdx.x * 256 + threadIdx.x) * 8;
  float4 v0 = ((const float4*)(x + i))[0];
  float4 v1 = ((const float4*)(x + i))[1];
  float f[8] = {v0.x, v0.y, v0.z, v0.w, v1.x, v1.y, v1.z, v1.w};
  int q1[8], q2[8];
#pragma unroll
  for (int j = 0; j < 8; j++) qsplit(f[j], SQ, SQ_INV, SQ2_INV, q1[j], q2[j]);
  uint2 ua, ub;
  ua.x = pack4(q1[0], q1[1], q1[2], q1[3]); ua.y = pack4(q1[4], q1[5], q1[6], q1[7]);
  ub.x = pack4(q2[0], q2[1], q2[2], q2[3]); ub.y = pack4(q2[4], q2[5], q2[6], q2[7]);
  *(uint2*)(a + i) = ua;
  *(uint2*)(b + i) = ub;
}

// ---- K: one pass -> K1/K2 [t][d] + KT1/KT2 [d][t] int8 ----
__global__ __launch_bounds__(256) void cvt_k_i8(const float* __restrict__ K,
                                                s8* __restrict__ k1, s8* __restrict__ k2,
                                                s8* __restrict__ t1, s8* __restrict__ t2) {
  __shared__ uint32_t tile[64][33];  // low byte q1, next byte q2
  const int b = blockIdx.z;
  const int d0 = blockIdx.x * 32, t0 = blockIdx.y * 64;
  const int tid = threadIdx.x;
  const float* Kb = K + (size_t)b * 2048 * 1024;
  {
    const int t = tid >> 2, d8 = (tid & 3) * 8;
    const float* src = Kb + (size_t)(t0 + t) * 1024 + d0 + d8;
    float4 v0 = ((const float4*)src)[0];
    float4 v1 = ((const float4*)src)[1];
    float f[8] = {v0.x, v0.y, v0.z, v0.w, v1.x, v1.y, v1.z, v1.w};
    int q1[8], q2[8];
#pragma unroll
    for (int j = 0; j < 8; j++) {
      qsplit(f[j], SQ, SQ_INV, SQ2_INV, q1[j], q2[j]);
      tile[t][d8 + j] = ((uint32_t)(uint8_t)q1[j]) | ((uint32_t)(uint8_t)q2[j] << 8);
    }
    uint2 ua, ub;
    ua.x = pack4(q1[0], q1[1], q1[2], q1[3]); ua.y = pack4(q1[4], q1[5], q1[6], q1[7]);
    ub.x = pack4(q2[0], q2[1], q2[2], q2[3]); ub.y = pack4(q2[4], q2[5], q2[6], q2[7]);
    size_t off = (size_t)b * 2048 * 1024 + (size_t)(t0 + t) * 1024 + d0 + d8;
    *(uint2*)(k1 + off) = ua;
    *(uint2*)(k2 + off) = ub;
  }
  __syncthreads();
  {
    const int d = tid >> 3, tg = tid & 7;
    uint32_t v[8];
#pragma unroll
    for (int i = 0; i < 8; i++) v[i] = tile[tg * 8 + i][d];
    uint2 ua, ub;
    ua.x = pack4(v[0], v[1], v[2], v[3]); ua.y = pack4(v[4], v[5], v[6], v[7]);
    ub.x = pack4(v[0] >> 8, v[1] >> 8, v[2] >> 8, v[3] >> 8);
    ub.y = pack4(v[4] >> 8, v[5] >> 8, v[6] >> 8, v[7] >> 8);
    size_t off = (size_t)b * 1024 * 2048 + (size_t)(d0 + d) * 2048 + t0 + tg * 8;
    *(uint2*)(t1 + off) = ua;
    *(uint2*)(t2 + off) = ub;
  }
}

// ---- row softmax: E fp32 [rows][2048] -> P1,P2 int8 (P ~= (p1 + p2/128)/127) ----
__global__ __launch_bounds__(256) void softmax_i8(const float* __restrict__ E,
                                                  s8* __restrict__ P1, s8* __restrict__ P2) {
  const size_t row = blockIdx.x;
  const float* e = E + row * 2048;
  const int t = threadIdx.x;
  float4 a = ((const float4*)e)[t * 2];
  float4 b = ((const float4*)e)[t * 2 + 1];
  float f[8] = {a.x, a.y, a.z, a.w, b.x, b.y, b.z, b.w};
  float m = f[0];
#pragma unroll
  for (int j = 1; j < 8; j++) m = fmaxf(m, f[j]);
#pragma unroll
  for (int off = 32; off > 0; off >>= 1) m = fmaxf(m, __shfl_down(m, off));
  __shared__ float redm[4], reds[4];
  if ((t & 63) == 0) redm[t >> 6] = m;
  __syncthreads();
  m = fmaxf(fmaxf(redm[0], redm[1]), fmaxf(redm[2], redm[3]));
  float ex[8];
  float s = 0.f;
#pragma unroll
  for (int j = 0; j < 8; j++) { ex[j] = __expf(f[j] - m); s += ex[j]; }
#pragma unroll
  for (int off = 32; off > 0; off >>= 1) s += __shfl_down(s, off);
  if ((t & 63) == 0) reds[t >> 6] = s;
  __syncthreads();
  s = reds[0] + reds[1] + reds[2] + reds[3];
  float inv = 1.0f / s;
  int q1[8], q2[8];
#pragma unroll
  for (int j = 0; j < 8; j++)
    qsplit(ex[j] * inv, 1.0f / 127.0f, 127.0f, 16256.0f, q1[j], q2[j]);
  uint2 ua, ub;
  ua.x = pack4(q1[0], q1[1], q1[2], q1[3]); ua.y = pack4(q1[4], q1[5], q1[6], q1[7]);
  ub.x = pack4(q2[0], q2[1], q2[2], q2[3]); ub.y = pack4(q2[4], q2[5], q2[6], q2[7]);
  *(uint2*)(P1 + row * 2048 + t * 8) = ua;
  *(uint2*)(P2 + row * 2048 + t * 8) = ub;
}

// ---- GEMM1 (int8): E = c1*(A1.B1^T) + c2*(A1.B2^T + A2.B1^T) ----
// 128x128 tile, BK=64. Double-buffered LDS + prefetch: at 1 block/CU there is
// no TLP to hide the global_load_lds drain, so tile t+1's loads are issued
// BEFORE tile t's MFMA cluster and the (implicit) vmcnt(0) drain at the
// end-of-iter __syncthreads overlaps with ~1000cy of compute.
__global__ __launch_bounds__(256) void gemm1_i8(
    const s8* __restrict__ A0, const s8* __restrict__ A1,
    const s8* __restrict__ B0, const s8* __restrict__ B1,
    float* __restrict__ C, int Kdim, int ldc, long sA, long sB, long sC) {
  __shared__ char lds[2][32768];
  const int tid = threadIdx.x;
  const int w = tid >> 6, l = tid & 63;
  const int bz = blockIdx.z;
  const int rowA = blockIdx.y * 128, rowB = blockIdx.x * 128;
  const s8* bases[4] = {A0 + bz * sA, A1 + bz * sA, B0 + bz * sB, B1 + bz * sB};
  const int rbase[4] = {rowA, rowA, rowB, rowB};
  const s8* gp[8];
  uint32_t lpo[8];
#pragma unroll
  for (int i = 0; i < 8; i++) {
    int gc = w * 8 + i;
    int buf = gc >> 3, c = gc & 7;
    int row = c * 16 + (l >> 2);
    int q = (l & 3) ^ ((row >> 1) & 3);
    gp[i] = bases[buf] + (size_t)(rbase[buf] + row) * Kdim + q * 16;
    lpo[i] = (uint32_t)(uintptr_t)(&lds[0][0] + buf * 8192 + c * 1024 + l * 16);
  }
  i32x4 acc1[4][4], acc2[4][4];
  const i32x4 zero = {0, 0, 0, 0};
#pragma unroll
  for (int mt = 0; mt < 4; mt++)
#pragma unroll
    for (int nt = 0; nt < 4; nt++) { acc1[mt][nt] = zero; acc2[mt][nt] = zero; }

  const int wm = w & 1, wn = w >> 1, q4 = l >> 4, rl = l & 15;

  // prologue: stage tile 0 into buffer 0
#pragma unroll
  for (int i = 0; i < 8; i++) { gload_lds16(gp[i], lpo[i]); gp[i] += 64; }
  __syncthreads();  // drains vmcnt(0)

  int cur = 0;
  for (int k0 = 0; k0 < Kdim; k0 += 64) {
    // issue prefetch of tile t+1 into the other buffer FIRST
    if (k0 + 64 < Kdim) {
      const uint32_t nb = (uint32_t)(cur ^ 1) * 32768u;
#pragma unroll
      for (int i = 0; i < 8; i++) { gload_lds16(gp[i], lpo[i] + nb); gp[i] += 64; }
    }
    const char* L = &lds[cur][0];
    i32x4 af[2][4], bfr[2][4];
#pragma unroll
    for (int mt = 0; mt < 4; mt++) {
      int row = wm * 64 + mt * 16 + rl;
      int off = row * 64 + ((q4 ^ ((row >> 1) & 3)) << 4);
      af[0][mt] = *(const i32x4*)(L + off);
      af[1][mt] = *(const i32x4*)(L + 8192 + off);
    }
#pragma unroll
    for (int nt = 0; nt < 4; nt++) {
      int row = wn * 64 + nt * 16 + rl;
      int off = row * 64 + ((q4 ^ ((row >> 1) & 3)) << 4);
      bfr[0][nt] = *(const i32x4*)(L + 16384 + off);
      bfr[1][nt] = *(const i32x4*)(L + 24576 + off);
    }
#pragma unroll
    for (int mt = 0; mt < 4; mt++)
#pragma unroll
      for (int nt = 0; nt < 4; nt++) {
        acc1[mt][nt] = __builtin_amdgcn_mfma_i32_16x16x64_i8(af[0][mt], bfr[0][nt], acc1[mt][nt], 0, 0, 0);
        acc2[mt][nt] = __builtin_amdgcn_mfma_i32_16x16x64_i8(af[0][mt], bfr[1][nt], acc2[mt][nt], 0, 0, 0);
        acc2[mt][nt] = __builtin_amdgcn_mfma_i32_16x16x64_i8(af[1][mt], bfr[0][nt], acc2[mt][nt], 0, 0, 0);
      }
    __syncthreads();  // waits vmcnt(0): prefetch had the whole MFMA cluster to land
    cur ^= 1;
  }
  const float c1 = 64.0f / 16129.0f, c2 = c1 * (1.0f / 128.0f);
  float* Cb = C + (size_t)bz * sC + (size_t)rowA * ldc + rowB;
#pragma unroll
  for (int mt = 0; mt < 4; mt++)
#pragma unroll
    for (int nt = 0; nt < 4; nt++)
#pragma unroll
      for (int r = 0; r < 4; r++)
        Cb[(size_t)(wm * 64 + mt * 16 + q4 * 4 + r) * ldc + (wn * 64 + nt * 16 + rl)] =
            c1 * (float)acc1[mt][nt][r] + c2 * (float)acc2[mt][nt][r];
}

// ---- GEMM2 (int8): O = c1*(P1.KT1^T) + c2*(P1.KT2^T + P2.KT1^T) ----
// 128(m) x 64(n) tile, BK=64; same double-buffer + prefetch restructure.
__global__ __launch_bounds__(256) void gemm2_i8(
    const s8* __restrict__ A0, const s8* __restrict__ A1,
    const s8* __restrict__ B0, const s8* __restrict__ B1,
    float* __restrict__ C, int Kdim, int ldc, long sA, long sB, long sC) {
  __shared__ char lds[2][24576];  // per buf: P1@0 (8KB), P2@8192, K1@16384 (4KB), K2@20480
  const int tid = threadIdx.x;
  const int w = tid >> 6, l = tid & 63;
  const int bz = blockIdx.z;
  const int rowA = blockIdx.y * 128, rowB = blockIdx.x * 64;
  const s8* bases[4] = {A0 + bz * sA, A1 + bz * sA, B0 + bz * sB, B1 + bz * sB};
  const int rbase[4] = {rowA, rowA, rowB, rowB};
  const int bufoff[4] = {0, 8192, 16384, 20480};
  const s8* gp[6];
  uint32_t lpo[6];
#pragma unroll
  for (int i = 0; i < 6; i++) {
    int gc = w * 6 + i;
    int buf, c;
    if (gc < 8) { buf = 0; c = gc; }
    else if (gc < 16) { buf = 1; c = gc - 8; }
    else if (gc < 20) { buf = 2; c = gc - 16; }
    else { buf = 3; c = gc - 20; }
    int row = c * 16 + (l >> 2);
    int q = (l & 3) ^ ((row >> 1) & 3);
    gp[i] = bases[buf] + (size_t)(rbase[buf] + row) * Kdim + q * 16;
    lpo[i] = (uint32_t)(uintptr_t)(&lds[0][0] + bufoff[buf] + c * 1024 + l * 16);
  }
  i32x4 acc1[4][2], acc2[4][2];
  const i32x4 zero = {0, 0, 0, 0};
#pragma unroll
  for (int mt = 0; mt < 4; mt++)
#pragma unroll
    for (int nt = 0; nt < 2; nt++) { acc1[mt][nt] = zero; acc2[mt][nt] = zero; }

  const int wm = w & 1, wn = w >> 1, q4 = l >> 4, rl = l & 15;

  // prologue: stage tile 0 into buffer 0
#pragma unroll
  for (int i = 0; i < 6; i++) { gload_lds16(gp[i], lpo[i]); gp[i] += 64; }
  __syncthreads();

  int cur = 0;
  for (int k0 = 0; k0 < Kdim; k0 += 64) {
    if (k0 + 64 < Kdim) {
      const uint32_t nb = (uint32_t)(cur ^ 1) * 24576u;
#pragma unroll
      for (int i = 0; i < 6; i++) { gload_lds16(gp[i], lpo[i] + nb); gp[i] += 64; }
    }
    const char* L = &lds[cur][0];
    i32x4 af[2][4], bfr[2][2];
#pragma unroll
    for (int mt = 0; mt < 4; mt++) {
      int row = wm * 64 + mt * 16 + rl;
      int off = row * 64 + ((q4 ^ ((row >> 1) & 3)) << 4);
      af[0][mt] = *(const i32x4*)(L + off);
      af[1][mt] = *(const i32x4*)(L + 8192 + off);
    }
#pragma unroll
    for (int nt = 0; nt < 2; nt++) {
      int row = wn * 32 + nt * 16 + rl;
      int off = row * 64 + ((q4 ^ ((row >> 1) & 3)) << 4);
      bfr[0][nt] = *(const i32x4*)(L + 16384 + off);
      bfr[1][nt] = *(const i32x4*)(L + 20480 + off);
    }
#pragma unroll
    for (int mt = 0; mt < 4; mt++)
#pragma unroll
      for (int nt = 0; nt < 2; nt++) {
        acc1[mt][nt] = __builtin_amdgcn_mfma_i32_16x16x64_i8(af[0][mt], bfr[0][nt], acc1[mt][nt], 0, 0, 0);
        acc2[mt][nt] = __builtin_amdgcn_mfma_i32_16x16x64_i8(af[0][mt], bfr[1][nt], acc2[mt][nt], 0, 0, 0);
        acc2[mt][nt] = __builtin_amdgcn_mfma_i32_16x16x64_i8(af[1][mt], bfr[0][nt], acc2[mt][nt], 0, 0, 0);
      }
    __syncthreads();
    cur ^= 1;
  }
  const float c1 = 8.0f / 16129.0f, c2 = c1 * (1.0f / 128.0f);
  float* Cb = C + (size_t)bz * sC + (size_t)rowA * ldc + rowB;
#pragma unroll
  for (int mt = 0; mt < 4; mt++)
#pragma unroll
    for (int nt = 0; nt < 2; nt++)
#pragma unroll
      for (int r = 0; r < 4; r++)
        Cb[(size_t)(wm * 64 + mt * 16 + q4 * 4 + r) * ldc + (wn * 32 + nt * 16 + rl)] =
            c1 * (float)acc1[mt][nt][r] + c2 * (float)acc2[mt][nt][r];
}

extern "C" void kernel_launch(void* const* d_in, const int* in_sizes, int n_in,
                              void* d_out, int out_size, void* d_ws, size_t ws_size,
                              hipStream_t stream) {
  (void)in_sizes; (void)n_in; (void)out_size;
  const float* Q = (const float*)d_in[0];
  const float* K = (const float*)d_in[1];
  float* O = (float*)d_out;
  const int Btot = 8, Tq = 2048, Tk = 2048, D = 1024;
  // ws per batch: Q1,Q2,K1,K2,KT1,KT2 int8 (2MB each) + E fp32 16MB + P1,P2 int8 (4MB each) = 36MB
  const size_t perb = 36ull << 20;
  int NB = 8;
  while (NB > 1 && (size_t)NB * perb > ws_size) NB >>= 1;

  char* p = (char*)d_ws;
  const size_t qd = (size_t)NB * Tq * D;
  const size_t kd = (size_t)NB * Tk * D;
  const size_t ee = (size_t)NB * Tq * Tk;
  s8* Q1 = (s8*)p; p += qd;
  s8* Q2 = (s8*)p; p += qd;
  s8* K1 = (s8*)p; p += kd;
  s8* K2 = (s8*)p; p += kd;
  s8* KT1 = (s8*)p; p += kd;
  s8* KT2 = (s8*)p; p += kd;
  float* E = (float*)p; p += ee * 4;
  s8* P1 = (s8*)p; p += ee;
  s8* P2 = (s8*)p; p += ee;

  for (int c = 0; c < Btot / NB; c++) {
    const float* Qc = Q + (size_t)c * qd;
    const float* Kc = K + (size_t)c * kd;
    float* Oc = O + (size_t)c * qd;
    cvt_q_i8<<<dim3(NB * 1024), 256, 0, stream>>>(Qc, Q1, Q2);
    cvt_k_i8<<<dim3(32, 32, NB), 256, 0, stream>>>(Kc, K1, K2, KT1, KT2);
    gemm1_i8<<<dim3(16, 16, NB), 256, 0, stream>>>(
        Q1, Q2, K1, K2, E, 1024, 2048, (long)Tq * D, (long)Tk * D, (long)Tq * Tk);
    softmax_i8<<<dim3(NB * Tq), 256, 0, stream>>>(E, P1, P2);
    gemm2_i8<<<dim3(16, 16, NB), 256, 0, stream>>>(
        P1, P2, KT1, KT2, Oc, 2048, 1024, (long)Tq * Tk, (long)D * Tk, (long)Tq * D);
  }
}

// Round 3
// 435.488 us; speedup vs baseline: 1.2927x; 1.0986x over previous
//
#include <hip/hip_runtime.h>
#include <stdint.h>

typedef int i32x4 __attribute__((ext_vector_type(4)));
typedef int8_t s8;

// ---- async global->LDS, 16B per lane ----
__device__ __forceinline__ void gload_lds16(const void* g, uint32_t lds_addr) {
  __builtin_amdgcn_global_load_lds(
      (const __attribute__((address_space(1))) void*)(uintptr_t)g,
      (__attribute__((address_space(3))) void*)(uintptr_t)lds_addr,
      16, 0, 0);
}

// ---- 2-level int8 split: x ~= s*(q1 + q2/128), |err| <= s/512 ----
__device__ __forceinline__ void qsplit(float x, float s, float sinv, float s2inv,
                                       int& q1, int& q2) {
  float a = rintf(x * sinv);
  a = fminf(fmaxf(a, -127.f), 127.f);
  float r = fmaf(a, -s, x);
  float b = fminf(fmaxf(rintf(r * s2inv), -127.f), 127.f);
  q1 = (int)a; q2 = (int)b;
}
__device__ __forceinline__ uint32_t pack4(int b0, int b1, int b2, int b3) {
  return ((uint32_t)(uint8_t)b0) | ((uint32_t)(uint8_t)b1 << 8) |
         ((uint32_t)(uint8_t)b2 << 16) | ((uint32_t)(uint8_t)b3 << 24);
}

#define SQ (8.0f / 127.0f)
#define SQ_INV 15.875f
#define SQ2_INV 2032.0f

// ---- Q: fp32 -> q1,q2 int8; 8 elems/thread ----
__global__ __launch_bounds__(256) void cvt_q_i8(const float* __restrict__ x,
                                                s8* __restrict__ a, s8* __restrict__ b) {
  size_t i = ((size_t)blockIdx.x * 256 + threadIdx.x) * 8;
  float4 v0 = ((const float4*)(x + i))[0];
  float4 v1 = ((const float4*)(x + i))[1];
  float f[8] = {v0.x, v0.y, v0.z, v0.w, v1.x, v1.y, v1.z, v1.w};
  int q1[8], q2[8];
#pragma unroll
  for (int j = 0; j < 8; j++) qsplit(f[j], SQ, SQ_INV, SQ2_INV, q1[j], q2[j]);
  uint2 ua, ub;
  ua.x = pack4(q1[0], q1[1], q1[2], q1[3]); ua.y = pack4(q1[4], q1[5], q1[6], q1[7]);
  ub.x = pack4(q2[0], q2[1], q2[2], q2[3]); ub.y = pack4(q2[4], q2[5], q2[6], q2[7]);
  *(uint2*)(a + i) = ua;
  *(uint2*)(b + i) = ub;
}

// ---- K: one pass -> K1/K2 [t][d] + KT1/KT2 [d][t] int8 ----
__global__ __launch_bounds__(256) void cvt_k_i8(const float* __restrict__ K,
                                                s8* __restrict__ k1, s8* __restrict__ k2,
                                                s8* __restrict__ t1, s8* __restrict__ t2) {
  __shared__ uint32_t tile[64][33];  // low byte q1, next byte q2
  const int b = blockIdx.z;
  const int d0 = blockIdx.x * 32, t0 = blockIdx.y * 64;
  const int tid = threadIdx.x;
  const float* Kb = K + (size_t)b * 2048 * 1024;
  {
    const int t = tid >> 2, d8 = (tid & 3) * 8;
    const float* src = Kb + (size_t)(t0 + t) * 1024 + d0 + d8;
    float4 v0 = ((const float4*)src)[0];
    float4 v1 = ((const float4*)src)[1];
    float f[8] = {v0.x, v0.y, v0.z, v0.w, v1.x, v1.y, v1.z, v1.w};
    int q1[8], q2[8];
#pragma unroll
    for (int j = 0; j < 8; j++) {
      qsplit(f[j], SQ, SQ_INV, SQ2_INV, q1[j], q2[j]);
      tile[t][d8 + j] = ((uint32_t)(uint8_t)q1[j]) | ((uint32_t)(uint8_t)q2[j] << 8);
    }
    uint2 ua, ub;
    ua.x = pack4(q1[0], q1[1], q1[2], q1[3]); ua.y = pack4(q1[4], q1[5], q1[6], q1[7]);
    ub.x = pack4(q2[0], q2[1], q2[2], q2[3]); ub.y = pack4(q2[4], q2[5], q2[6], q2[7]);
    size_t off = (size_t)b * 2048 * 1024 + (size_t)(t0 + t) * 1024 + d0 + d8;
    *(uint2*)(k1 + off) = ua;
    *(uint2*)(k2 + off) = ub;
  }
  __syncthreads();
  {
    const int d = tid >> 3, tg = tid & 7;
    uint32_t v[8];
#pragma unroll
    for (int i = 0; i < 8; i++) v[i] = tile[tg * 8 + i][d];
    uint2 ua, ub;
    ua.x = pack4(v[0], v[1], v[2], v[3]); ua.y = pack4(v[4], v[5], v[6], v[7]);
    ub.x = pack4(v[0] >> 8, v[1] >> 8, v[2] >> 8, v[3] >> 8);
    ub.y = pack4(v[4] >> 8, v[5] >> 8, v[6] >> 8, v[7] >> 8);
    size_t off = (size_t)b * 1024 * 2048 + (size_t)(d0 + d) * 2048 + t0 + tg * 8;
    *(uint2*)(t1 + off) = ua;
    *(uint2*)(t2 + off) = ub;
  }
}

// ---- row softmax: E fp32 [rows][2048] -> P1,P2 int8 (P ~= (p1 + p2/128)/127) ----
__global__ __launch_bounds__(256) void softmax_i8(const float* __restrict__ E,
                                                  s8* __restrict__ P1, s8* __restrict__ P2) {
  const size_t row = blockIdx.x;
  const float* e = E + row * 2048;
  const int t = threadIdx.x;
  float4 a = ((const float4*)e)[t * 2];
  float4 b = ((const float4*)e)[t * 2 + 1];
  float f[8] = {a.x, a.y, a.z, a.w, b.x, b.y, b.z, b.w};
  float m = f[0];
#pragma unroll
  for (int j = 1; j < 8; j++) m = fmaxf(m, f[j]);
#pragma unroll
  for (int off = 32; off > 0; off >>= 1) m = fmaxf(m, __shfl_down(m, off));
  __shared__ float redm[4], reds[4];
  if ((t & 63) == 0) redm[t >> 6] = m;
  __syncthreads();
  m = fmaxf(fmaxf(redm[0], redm[1]), fmaxf(redm[2], redm[3]));
  float ex[8];
  float s = 0.f;
#pragma unroll
  for (int j = 0; j < 8; j++) { ex[j] = __expf(f[j] - m); s += ex[j]; }
#pragma unroll
  for (int off = 32; off > 0; off >>= 1) s += __shfl_down(s, off);
  if ((t & 63) == 0) reds[t >> 6] = s;
  __syncthreads();
  s = reds[0] + reds[1] + reds[2] + reds[3];
  float inv = 1.0f / s;
  int q1[8], q2[8];
#pragma unroll
  for (int j = 0; j < 8; j++)
    qsplit(ex[j] * inv, 1.0f / 127.0f, 127.0f, 16256.0f, q1[j], q2[j]);
  uint2 ua, ub;
  ua.x = pack4(q1[0], q1[1], q1[2], q1[3]); ua.y = pack4(q1[4], q1[5], q1[6], q1[7]);
  ub.x = pack4(q2[0], q2[1], q2[2], q2[3]); ub.y = pack4(q2[4], q2[5], q2[6], q2[7]);
  *(uint2*)(P1 + row * 2048 + t * 8) = ua;
  *(uint2*)(P2 + row * 2048 + t * 8) = ub;
}

// ---- GEMM1 (int8): E = c1*(A1.B1^T) + c2*(A1.B2^T + A2.B1^T) ----
// 128x128 tile, BK=64, 8 waves (512 thr) -> 64 AGPR acc/wave => 2 waves/SIMD.
// Two-barrier counted-vmcnt pipeline (builtin barriers, m201-template idiom):
// tile t's loads get a full iteration of slack; t+1's stay in flight across
// the barrier (vmcnt(4), never 0 in the main loop).
__global__ __launch_bounds__(512, 2) void gemm1_i8(
    const s8* __restrict__ A0, const s8* __restrict__ A1,
    const s8* __restrict__ B0, const s8* __restrict__ B1,
    float* __restrict__ C, int Kdim, int ldc, long sA, long sB, long sC) {
  __shared__ char lds[2][32768];
  const int tid = threadIdx.x;
  const int w = tid >> 6, l = tid & 63;
  const int bz = blockIdx.z;
  const int rowA = blockIdx.y * 128, rowB = blockIdx.x * 128;
  const s8* bases[4] = {A0 + bz * sA, A1 + bz * sA, B0 + bz * sB, B1 + bz * sB};
  const int rbase[4] = {rowA, rowA, rowB, rowB};
  const s8* gp[4];
  uint32_t lpo[4];
#pragma unroll
  for (int i = 0; i < 4; i++) {
    int gc = w * 4 + i;                 // 32 chunks of 1KB over 8 waves
    int buf = gc >> 3, c = gc & 7;
    int row = c * 16 + (l >> 2);
    int q = (l & 3) ^ ((row >> 1) & 3);
    gp[i] = bases[buf] + (size_t)(rbase[buf] + row) * Kdim + q * 16;
    lpo[i] = (uint32_t)(uintptr_t)(&lds[0][0] + buf * 8192 + c * 1024 + l * 16);
  }
  i32x4 acc1[4][2], acc2[4][2];
  const i32x4 zero = {0, 0, 0, 0};
#pragma unroll
  for (int mt = 0; mt < 4; mt++)
#pragma unroll
    for (int nt = 0; nt < 2; nt++) { acc1[mt][nt] = zero; acc2[mt][nt] = zero; }

  const int wm = w >> 2, wn = w & 3, q4 = l >> 4, rl = l & 15;

  // prologue: stage tile 0 into buffer 0
#pragma unroll
  for (int i = 0; i < 4; i++) { gload_lds16(gp[i], lpo[i]); gp[i] += 64; }

  int cur = 0;
  for (int k0 = 0; k0 < Kdim; k0 += 64) {
    // barrier A: all waves done ds_reading buf[cur^1] (iter t-1) before overwrite
    __builtin_amdgcn_s_barrier();
    if (k0 + 64 < Kdim) {
      const uint32_t nb = (uint32_t)(cur ^ 1) * 32768u;
#pragma unroll
      for (int i = 0; i < 4; i++) { gload_lds16(gp[i], lpo[i] + nb); gp[i] += 64; }
      // own tile-t loads done (4 newest = t+1's stay in flight)
      asm volatile("s_waitcnt vmcnt(4)" ::: "memory");
    } else {
      asm volatile("s_waitcnt vmcnt(0)" ::: "memory");
    }
    __builtin_amdgcn_sched_barrier(0);
    __builtin_amdgcn_s_barrier();  // barrier B: buf[cur] fully staged for all
    const char* L = &lds[cur][0];
    i32x4 af[2][4], bfr[2][2];
#pragma unroll
    for (int mt = 0; mt < 4; mt++) {
      int row = wm * 64 + mt * 16 + rl;
      int off = row * 64 + ((q4 ^ ((row >> 1) & 3)) << 4);
      af[0][mt] = *(const i32x4*)(L + off);
      af[1][mt] = *(const i32x4*)(L + 8192 + off);
    }
#pragma unroll
    for (int nt = 0; nt < 2; nt++) {
      int row = wn * 32 + nt * 16 + rl;
      int off = row * 64 + ((q4 ^ ((row >> 1) & 3)) << 4);
      bfr[0][nt] = *(const i32x4*)(L + 16384 + off);
      bfr[1][nt] = *(const i32x4*)(L + 24576 + off);
    }
#pragma unroll
    for (int mt = 0; mt < 4; mt++)
#pragma unroll
      for (int nt = 0; nt < 2; nt++) {
        acc1[mt][nt] = __builtin_amdgcn_mfma_i32_16x16x64_i8(af[0][mt], bfr[0][nt], acc1[mt][nt], 0, 0, 0);
        acc2[mt][nt] = __builtin_amdgcn_mfma_i32_16x16x64_i8(af[0][mt], bfr[1][nt], acc2[mt][nt], 0, 0, 0);
        acc2[mt][nt] = __builtin_amdgcn_mfma_i32_16x16x64_i8(af[1][mt], bfr[0][nt], acc2[mt][nt], 0, 0, 0);
      }
    cur ^= 1;
  }
  const float c1 = 64.0f / 16129.0f, c2 = c1 * (1.0f / 128.0f);
  float* Cb = C + (size_t)bz * sC + (size_t)rowA * ldc + rowB;
#pragma unroll
  for (int mt = 0; mt < 4; mt++)
#pragma unroll
    for (int nt = 0; nt < 2; nt++)
#pragma unroll
      for (int r = 0; r < 4; r++)
        Cb[(size_t)(wm * 64 + mt * 16 + q4 * 4 + r) * ldc + (wn * 32 + nt * 16 + rl)] =
            c1 * (float)acc1[mt][nt][r] + c2 * (float)acc2[mt][nt][r];
}

// ---- GEMM2 (int8): O = c1*(P1.KT1^T) + c2*(P1.KT2^T + P2.KT1^T) ----
// 128(m) x 64(n) tile, BK=64, 8 waves; same counted-vmcnt pipeline.
__global__ __launch_bounds__(512, 2) void gemm2_i8(
    const s8* __restrict__ A0, const s8* __restrict__ A1,
    const s8* __restrict__ B0, const s8* __restrict__ B1,
    float* __restrict__ C, int Kdim, int ldc, long sA, long sB, long sC) {
  __shared__ char lds[2][24576];  // per buf: P1@0 (8KB), P2@8192, K1@16384 (4KB), K2@20480
  const int tid = threadIdx.x;
  const int w = tid >> 6, l = tid & 63;
  const int bz = blockIdx.z;
  const int rowA = blockIdx.y * 128, rowB = blockIdx.x * 64;
  const s8* bases[4] = {A0 + bz * sA, A1 + bz * sA, B0 + bz * sB, B1 + bz * sB};
  const int rbase[4] = {rowA, rowA, rowB, rowB};
  const int bufoff[4] = {0, 8192, 16384, 20480};
  const s8* gp[3];
  uint32_t lpo[3];
#pragma unroll
  for (int i = 0; i < 3; i++) {
    int gc = w * 3 + i;                 // 24 chunks of 1KB over 8 waves
    int buf, c;
    if (gc < 8) { buf = 0; c = gc; }
    else if (gc < 16) { buf = 1; c = gc - 8; }
    else if (gc < 20) { buf = 2; c = gc - 16; }
    else { buf = 3; c = gc - 20; }
    int row = c * 16 + (l >> 2);
    int q = (l & 3) ^ ((row >> 1) & 3);
    gp[i] = bases[buf] + (size_t)(rbase[buf] + row) * Kdim + q * 16;
    lpo[i] = (uint32_t)(uintptr_t)(&lds[0][0] + bufoff[buf] + c * 1024 + l * 16);
  }
  i32x4 acc1[4], acc2[4];
  const i32x4 zero = {0, 0, 0, 0};
#pragma unroll
  for (int mt = 0; mt < 4; mt++) { acc1[mt] = zero; acc2[mt] = zero; }

  const int wm = w >> 2, wn = w & 3, q4 = l >> 4, rl = l & 15;

  // prologue: stage tile 0 into buffer 0
#pragma unroll
  for (int i = 0; i < 3; i++) { gload_lds16(gp[i], lpo[i]); gp[i] += 64; }

  int cur = 0;
  for (int k0 = 0; k0 < Kdim; k0 += 64) {
    __builtin_amdgcn_s_barrier();
    if (k0 + 64 < Kdim) {
      const uint32_t nb = (uint32_t)(cur ^ 1) * 24576u;
#pragma unroll
      for (int i = 0; i < 3; i++) { gload_lds16(gp[i], lpo[i] + nb); gp[i] += 64; }
      asm volatile("s_waitcnt vmcnt(3)" ::: "memory");
    } else {
      asm volatile("s_waitcnt vmcnt(0)" ::: "memory");
    }
    __builtin_amdgcn_sched_barrier(0);
    __builtin_amdgcn_s_barrier();
    const char* L = &lds[cur][0];
    i32x4 af[2][4], bf0, bf1;
#pragma unroll
    for (int mt = 0; mt < 4; mt++) {
      int row = wm * 64 + mt * 16 + rl;
      int off = row * 64 + ((q4 ^ ((row >> 1) & 3)) << 4);
      af[0][mt] = *(const i32x4*)(L + off);
      af[1][mt] = *(const i32x4*)(L + 8192 + off);
    }
    {
      int row = wn * 16 + rl;
      int off = row * 64 + ((q4 ^ ((row >> 1) & 3)) << 4);
      bf0 = *(const i32x4*)(L + 16384 + off);
      bf1 = *(const i32x4*)(L + 20480 + off);
    }
#pragma unroll
    for (int mt = 0; mt < 4; mt++) {
      acc1[mt] = __builtin_amdgcn_mfma_i32_16x16x64_i8(af[0][mt], bf0, acc1[mt], 0, 0, 0);
      acc2[mt] = __builtin_amdgcn_mfma_i32_16x16x64_i8(af[0][mt], bf1, acc2[mt], 0, 0, 0);
      acc2[mt] = __builtin_amdgcn_mfma_i32_16x16x64_i8(af[1][mt], bf0, acc2[mt], 0, 0, 0);
    }
    cur ^= 1;
  }
  const float c1 = 8.0f / 16129.0f, c2 = c1 * (1.0f / 128.0f);
  float* Cb = C + (size_t)bz * sC + (size_t)rowA * ldc + rowB;
#pragma unroll
  for (int mt = 0; mt < 4; mt++)
#pragma unroll
    for (int r = 0; r < 4; r++)
      Cb[(size_t)(wm * 64 + mt * 16 + q4 * 4 + r) * ldc + (wn * 16 + rl)] =
          c1 * (float)acc1[mt][r] + c2 * (float)acc2[mt][r];
}

extern "C" void kernel_launch(void* const* d_in, const int* in_sizes, int n_in,
                              void* d_out, int out_size, void* d_ws, size_t ws_size,
                              hipStream_t stream) {
  (void)in_sizes; (void)n_in; (void)out_size;
  const float* Q = (const float*)d_in[0];
  const float* K = (const float*)d_in[1];
  float* O = (float*)d_out;
  const int Btot = 8, Tq = 2048, Tk = 2048, D = 1024;
  // ws per batch: Q1,Q2,K1,K2,KT1,KT2 int8 (2MB each) + E fp32 16MB + P1,P2 int8 (4MB each) = 36MB
  const size_t perb = 36ull << 20;
  int NB = 8;
  while (NB > 1 && (size_t)NB * perb > ws_size) NB >>= 1;

  char* p = (char*)d_ws;
  const size_t qd = (size_t)NB * Tq * D;
  const size_t kd = (size_t)NB * Tk * D;
  const size_t ee = (size_t)NB * Tq * Tk;
  s8* Q1 = (s8*)p; p += qd;
  s8* Q2 = (s8*)p; p += qd;
  s8* K1 = (s8*)p; p += kd;
  s8* K2 = (s8*)p; p += kd;
  s8* KT1 = (s8*)p; p += kd;
  s8* KT2 = (s8*)p; p += kd;
  float* E = (float*)p; p += ee * 4;
  s8* P1 = (s8*)p; p += ee;
  s8* P2 = (s8*)p; p += ee;

  for (int c = 0; c < Btot / NB; c++) {
    const float* Qc = Q + (size_t)c * qd;
    const float* Kc = K + (size_t)c * kd;
    float* Oc = O + (size_t)c * qd;
    cvt_q_i8<<<dim3(NB * 1024), 256, 0, stream>>>(Qc, Q1, Q2);
    cvt_k_i8<<<dim3(32, 32, NB), 256, 0, stream>>>(Kc, K1, K2, KT1, KT2);
    gemm1_i8<<<dim3(16, 16, NB), 512, 0, stream>>>(
        Q1, Q2, K1, K2, E, 1024, 2048, (long)Tq * D, (long)Tk * D, (long)Tq * Tk);
    softmax_i8<<<dim3(NB * Tq), 256, 0, stream>>>(E, P1, P2);
    gemm2_i8<<<dim3(16, 16, NB), 512, 0, stream>>>(
        P1, P2, KT1, KT2, Oc, 2048, 1024, (long)Tq * Tk, (long)D * Tk, (long)Tq * D);
  }
}

// Round 4
// 427.042 us; speedup vs baseline: 1.3183x; 1.0198x over previous
//
#include <hip/hip_runtime.h>
#include <stdint.h>

typedef int i32x4 __attribute__((ext_vector_type(4)));
typedef int8_t s8;

// ---- async global->LDS, 16B per lane ----
__device__ __forceinline__ void gload_lds16(const void* g, uint32_t lds_addr) {
  __builtin_amdgcn_global_load_lds(
      (const __attribute__((address_space(1))) void*)(uintptr_t)g,
      (__attribute__((address_space(3))) void*)(uintptr_t)lds_addr,
      16, 0, 0);
}

// ---- 2-level int8 split: x ~= s*(q1 + q2/128), |err| <= s/512 ----
__device__ __forceinline__ void qsplit(float x, float s, float sinv, float s2inv,
                                       int& q1, int& q2) {
  float a = rintf(x * sinv);
  a = fminf(fmaxf(a, -127.f), 127.f);
  float r = fmaf(a, -s, x);
  float b = fminf(fmaxf(rintf(r * s2inv), -127.f), 127.f);
  q1 = (int)a; q2 = (int)b;
}
__device__ __forceinline__ uint32_t pack4(int b0, int b1, int b2, int b3) {
  return ((uint32_t)(uint8_t)b0) | ((uint32_t)(uint8_t)b1 << 8) |
         ((uint32_t)(uint8_t)b2 << 16) | ((uint32_t)(uint8_t)b3 << 24);
}

#define SQ (8.0f / 127.0f)
#define SQ_INV 15.875f
#define SQ2_INV 2032.0f

// ---- Q: fp32 -> q1,q2 int8; 8 elems/thread ----
__global__ __launch_bounds__(256) void cvt_q_i8(const float* __restrict__ x,
                                                s8* __restrict__ a, s8* __restrict__ b) {
  size_t i = ((size_t)blockIdx.x * 256 + threadIdx.x) * 8;
  float4 v0 = ((const float4*)(x + i))[0];
  float4 v1 = ((const float4*)(x + i))[1];
  float f[8] = {v0.x, v0.y, v0.z, v0.w, v1.x, v1.y, v1.z, v1.w};
  int q1[8], q2[8];
#pragma unroll
  for (int j = 0; j < 8; j++) qsplit(f[j], SQ, SQ_INV, SQ2_INV, q1[j], q2[j]);
  uint2 ua, ub;
  ua.x = pack4(q1[0], q1[1], q1[2], q1[3]); ua.y = pack4(q1[4], q1[5], q1[6], q1[7]);
  ub.x = pack4(q2[0], q2[1], q2[2], q2[3]); ub.y = pack4(q2[4], q2[5], q2[6], q2[7]);
  *(uint2*)(a + i) = ua;
  *(uint2*)(b + i) = ub;
}

// ---- K: one pass -> K1/K2 [t][d] + KT1/KT2 [d][t] int8 ----
__global__ __launch_bounds__(256) void cvt_k_i8(const float* __restrict__ K,
                                                s8* __restrict__ k1, s8* __restrict__ k2,
                                                s8* __restrict__ t1, s8* __restrict__ t2) {
  __shared__ uint32_t tile[64][33];  // low byte q1, next byte q2
  const int b = blockIdx.z;
  const int d0 = blockIdx.x * 32, t0 = blockIdx.y * 64;
  const int tid = threadIdx.x;
  const float* Kb = K + (size_t)b * 2048 * 1024;
  {
    const int t = tid >> 2, d8 = (tid & 3) * 8;
    const float* src = Kb + (size_t)(t0 + t) * 1024 + d0 + d8;
    float4 v0 = ((const float4*)src)[0];
    float4 v1 = ((const float4*)src)[1];
    float f[8] = {v0.x, v0.y, v0.z, v0.w, v1.x, v1.y, v1.z, v1.w};
    int q1[8], q2[8];
#pragma unroll
    for (int j = 0; j < 8; j++) {
      qsplit(f[j], SQ, SQ_INV, SQ2_INV, q1[j], q2[j]);
      tile[t][d8 + j] = ((uint32_t)(uint8_t)q1[j]) | ((uint32_t)(uint8_t)q2[j] << 8);
    }
    uint2 ua, ub;
    ua.x = pack4(q1[0], q1[1], q1[2], q1[3]); ua.y = pack4(q1[4], q1[5], q1[6], q1[7]);
    ub.x = pack4(q2[0], q2[1], q2[2], q2[3]); ub.y = pack4(q2[4], q2[5], q2[6], q2[7]);
    size_t off = (size_t)b * 2048 * 1024 + (size_t)(t0 + t) * 1024 + d0 + d8;
    *(uint2*)(k1 + off) = ua;
    *(uint2*)(k2 + off) = ub;
  }
  __syncthreads();
  {
    const int d = tid >> 3, tg = tid & 7;
    uint32_t v[8];
#pragma unroll
    for (int i = 0; i < 8; i++) v[i] = tile[tg * 8 + i][d];
    uint2 ua, ub;
    ua.x = pack4(v[0], v[1], v[2], v[3]); ua.y = pack4(v[4], v[5], v[6], v[7]);
    ub.x = pack4(v[0] >> 8, v[1] >> 8, v[2] >> 8, v[3] >> 8);
    ub.y = pack4(v[4] >> 8, v[5] >> 8, v[6] >> 8, v[7] >> 8);
    size_t off = (size_t)b * 1024 * 2048 + (size_t)(d0 + d) * 2048 + t0 + tg * 8;
    *(uint2*)(t1 + off) = ua;
    *(uint2*)(t2 + off) = ub;
  }
}

// ---- row softmax: E fp32 [rows][2048] -> P1,P2 int8 (P ~= (p1 + p2/128)/127) ----
__global__ __launch_bounds__(256) void softmax_i8(const float* __restrict__ E,
                                                  s8* __restrict__ P1, s8* __restrict__ P2) {
  const size_t row = blockIdx.x;
  const float* e = E + row * 2048;
  const int t = threadIdx.x;
  float4 a = ((const float4*)e)[t * 2];
  float4 b = ((const float4*)e)[t * 2 + 1];
  float f[8] = {a.x, a.y, a.z, a.w, b.x, b.y, b.z, b.w};
  float m = f[0];
#pragma unroll
  for (int j = 1; j < 8; j++) m = fmaxf(m, f[j]);
#pragma unroll
  for (int off = 32; off > 0; off >>= 1) m = fmaxf(m, __shfl_down(m, off));
  __shared__ float redm[4], reds[4];
  if ((t & 63) == 0) redm[t >> 6] = m;
  __syncthreads();
  m = fmaxf(fmaxf(redm[0], redm[1]), fmaxf(redm[2], redm[3]));
  float ex[8];
  float s = 0.f;
#pragma unroll
  for (int j = 0; j < 8; j++) { ex[j] = __expf(f[j] - m); s += ex[j]; }
#pragma unroll
  for (int off = 32; off > 0; off >>= 1) s += __shfl_down(s, off);
  if ((t & 63) == 0) reds[t >> 6] = s;
  __syncthreads();
  s = reds[0] + reds[1] + reds[2] + reds[3];
  float inv = 1.0f / s;
  int q1[8], q2[8];
#pragma unroll
  for (int j = 0; j < 8; j++)
    qsplit(ex[j] * inv, 1.0f / 127.0f, 127.0f, 16256.0f, q1[j], q2[j]);
  uint2 ua, ub;
  ua.x = pack4(q1[0], q1[1], q1[2], q1[3]); ua.y = pack4(q1[4], q1[5], q1[6], q1[7]);
  ub.x = pack4(q2[0], q2[1], q2[2], q2[3]); ub.y = pack4(q2[4], q2[5], q2[6], q2[7]);
  *(uint2*)(P1 + row * 2048 + t * 8) = ua;
  *(uint2*)(P2 + row * 2048 + t * 8) = ub;
}

// ---- unified dual-int8 GEMM: C = c1*(A1.B1^T) + c2*(A1.B2^T + A2.B1^T) ----
// 128x128 tile, BK=64, 4 waves, wave tile 64x64 (2x2 wave grid).
// Rationale: LDS-read-roofline. ops/byte = 3MN/(M+N): 64x16 tile = 38 (round-3
// gemm2, LDS-bound at ~1900cy/slot vs 980cy MFMA); 64x64 = 96 -> MFMA-dominant.
// __launch_bounds__(256,2) pins VGPR<=128 (with 128 AGPR acc) so 2 blocks/CU
// co-reside: the independent second block covers this block's barriers.
// Counted-vmcnt double-buffer (round-3 pipeline, verified): prefetch t+1 before
// compute t; vmcnt(8) keeps t+1's loads in flight across the barrier.
__global__ __launch_bounds__(256, 2) void gemm_i8(
    const s8* __restrict__ A0, const s8* __restrict__ A1,
    const s8* __restrict__ B0, const s8* __restrict__ B1,
    float* __restrict__ C, int Kdim, int ldc, long sA, long sB, long sC,
    float c1, float c2) {
  __shared__ char lds[2][32768];  // per buf: A1@0, A2@8192, B1@16384, B2@24576
  const int tid = threadIdx.x;
  const int w = tid >> 6, l = tid & 63;
  const int bz = blockIdx.z;
  const int rowA = blockIdx.y * 128, rowB = blockIdx.x * 128;
  const s8* bases[4] = {A0 + bz * sA, A1 + bz * sA, B0 + bz * sB, B1 + bz * sB};
  const int rbase[4] = {rowA, rowA, rowB, rowB};
  const s8* gp[8];
  uint32_t lpo[8];
#pragma unroll
  for (int i = 0; i < 8; i++) {
    int gc = w * 8 + i;                 // 32 chunks of 1KB over 4 waves
    int buf = gc >> 3, c = gc & 7;
    int row = c * 16 + (l >> 2);
    int q = (l & 3) ^ ((row >> 1) & 3);
    gp[i] = bases[buf] + (size_t)(rbase[buf] + row) * Kdim + q * 16;
    lpo[i] = (uint32_t)(uintptr_t)(&lds[0][0] + buf * 8192 + c * 1024 + l * 16);
  }
  i32x4 acc1[4][4], acc2[4][4];
  const i32x4 zero = {0, 0, 0, 0};
#pragma unroll
  for (int mt = 0; mt < 4; mt++)
#pragma unroll
    for (int nt = 0; nt < 4; nt++) { acc1[mt][nt] = zero; acc2[mt][nt] = zero; }

  const int wm = w & 1, wn = w >> 1, q4 = l >> 4, rl = l & 15;

  // prologue: stage tile 0 into buffer 0
#pragma unroll
  for (int i = 0; i < 8; i++) { gload_lds16(gp[i], lpo[i]); gp[i] += 64; }

  int cur = 0;
  for (int k0 = 0; k0 < Kdim; k0 += 64) {
    // barrier A: all waves done reading buf[cur^1] before its overwrite begins
    __builtin_amdgcn_s_barrier();
    if (k0 + 64 < Kdim) {
      const uint32_t nb = (uint32_t)(cur ^ 1) * 32768u;
#pragma unroll
      for (int i = 0; i < 8; i++) { gload_lds16(gp[i], lpo[i] + nb); gp[i] += 64; }
      // wait own tile-t loads only (8 newest = t+1's stay in flight)
      asm volatile("s_waitcnt vmcnt(8)" ::: "memory");
    } else {
      asm volatile("s_waitcnt vmcnt(0)" ::: "memory");
    }
    __builtin_amdgcn_sched_barrier(0);
    __builtin_amdgcn_s_barrier();  // barrier B: buf[cur] fully staged for all
    const char* L = &lds[cur][0];
    i32x4 af0[4], af1[4];
#pragma unroll
    for (int mt = 0; mt < 4; mt++) {
      int row = wm * 64 + mt * 16 + rl;
      int off = row * 64 + ((q4 ^ ((row >> 1) & 3)) << 4);
      af0[mt] = *(const i32x4*)(L + off);
      af1[mt] = *(const i32x4*)(L + 8192 + off);
    }
#pragma unroll
    for (int nt = 0; nt < 4; nt++) {
      int row = wn * 64 + nt * 16 + rl;
      int off = row * 64 + ((q4 ^ ((row >> 1) & 3)) << 4);
      i32x4 bf0 = *(const i32x4*)(L + 16384 + off);
      i32x4 bf1 = *(const i32x4*)(L + 24576 + off);
#pragma unroll
      for (int mt = 0; mt < 4; mt++) {
        acc1[mt][nt] = __builtin_amdgcn_mfma_i32_16x16x64_i8(af0[mt], bf0, acc1[mt][nt], 0, 0, 0);
        acc2[mt][nt] = __builtin_amdgcn_mfma_i32_16x16x64_i8(af0[mt], bf1, acc2[mt][nt], 0, 0, 0);
        acc2[mt][nt] = __builtin_amdgcn_mfma_i32_16x16x64_i8(af1[mt], bf0, acc2[mt][nt], 0, 0, 0);
      }
    }
    cur ^= 1;
  }
  float* Cb = C + (size_t)bz * sC + (size_t)rowA * ldc + rowB;
#pragma unroll
  for (int mt = 0; mt < 4; mt++)
#pragma unroll
    for (int nt = 0; nt < 4; nt++)
#pragma unroll
      for (int r = 0; r < 4; r++)
        Cb[(size_t)(wm * 64 + mt * 16 + q4 * 4 + r) * ldc + (wn * 64 + nt * 16 + rl)] =
            c1 * (float)acc1[mt][nt][r] + c2 * (float)acc2[mt][nt][r];
}

extern "C" void kernel_launch(void* const* d_in, const int* in_sizes, int n_in,
                              void* d_out, int out_size, void* d_ws, size_t ws_size,
                              hipStream_t stream) {
  (void)in_sizes; (void)n_in; (void)out_size;
  const float* Q = (const float*)d_in[0];
  const float* K = (const float*)d_in[1];
  float* O = (float*)d_out;
  const int Btot = 8, Tq = 2048, Tk = 2048, D = 1024;
  // ws per batch: Q1,Q2,K1,K2,KT1,KT2 int8 (2MB each) + E fp32 16MB + P1,P2 int8 (4MB each) = 36MB
  const size_t perb = 36ull << 20;
  int NB = 8;
  while (NB > 1 && (size_t)NB * perb > ws_size) NB >>= 1;

  char* p = (char*)d_ws;
  const size_t qd = (size_t)NB * Tq * D;
  const size_t kd = (size_t)NB * Tk * D;
  const size_t ee = (size_t)NB * Tq * Tk;
  s8* Q1 = (s8*)p; p += qd;
  s8* Q2 = (s8*)p; p += qd;
  s8* K1 = (s8*)p; p += kd;
  s8* K2 = (s8*)p; p += kd;
  s8* KT1 = (s8*)p; p += kd;
  s8* KT2 = (s8*)p; p += kd;
  float* E = (float*)p; p += ee * 4;
  s8* P1 = (s8*)p; p += ee;
  s8* P2 = (s8*)p; p += ee;

  const float g1c1 = 64.0f / 16129.0f, g1c2 = g1c1 * (1.0f / 128.0f);
  const float g2c1 = 8.0f / 16129.0f, g2c2 = g2c1 * (1.0f / 128.0f);

  for (int c = 0; c < Btot / NB; c++) {
    const float* Qc = Q + (size_t)c * qd;
    const float* Kc = K + (size_t)c * kd;
    float* Oc = O + (size_t)c * qd;
    cvt_q_i8<<<dim3(NB * 1024), 256, 0, stream>>>(Qc, Q1, Q2);
    cvt_k_i8<<<dim3(32, 32, NB), 256, 0, stream>>>(Kc, K1, K2, KT1, KT2);
    gemm_i8<<<dim3(16, 16, NB), 256, 0, stream>>>(
        Q1, Q2, K1, K2, E, 1024, 2048, (long)Tq * D, (long)Tk * D, (long)Tq * Tk,
        g1c1, g1c2);
    softmax_i8<<<dim3(NB * Tq), 256, 0, stream>>>(E, P1, P2);
    gemm_i8<<<dim3(8, 16, NB), 256, 0, stream>>>(
        P1, P2, KT1, KT2, Oc, 2048, 1024, (long)Tq * Tk, (long)D * Tk, (long)Tq * D,
        g2c1, g2c2);
  }
}

// Round 5
// 404.349 us; speedup vs baseline: 1.3923x; 1.0561x over previous
//
#include <hip/hip_runtime.h>
#include <stdint.h>

typedef int i32x4 __attribute__((ext_vector_type(4)));
typedef int8_t s8;

// ---- async global->LDS, 16B per lane ----
__device__ __forceinline__ void gload_lds16(const void* g, uint32_t lds_addr) {
  __builtin_amdgcn_global_load_lds(
      (const __attribute__((address_space(1))) void*)(uintptr_t)g,
      (__attribute__((address_space(3))) void*)(uintptr_t)lds_addr,
      16, 0, 0);
}

// ---- 2-level int8 split: x ~= s*(q1 + q2/128), |err| <= s/512 ----
__device__ __forceinline__ void qsplit(float x, float s, float sinv, float s2inv,
                                       int& q1, int& q2) {
  float a = rintf(x * sinv);
  a = fminf(fmaxf(a, -127.f), 127.f);
  float r = fmaf(a, -s, x);
  float b = fminf(fmaxf(rintf(r * s2inv), -127.f), 127.f);
  q1 = (int)a; q2 = (int)b;
}
__device__ __forceinline__ uint32_t pack4(int b0, int b1, int b2, int b3) {
  return ((uint32_t)(uint8_t)b0) | ((uint32_t)(uint8_t)b1 << 8) |
         ((uint32_t)(uint8_t)b2 << 16) | ((uint32_t)(uint8_t)b3 << 24);
}

#define SQ (8.0f / 127.0f)
#define SQ_INV 15.875f
#define SQ2_INV 2032.0f

// ---- Q: fp32 -> q1,q2 int8; 8 elems/thread ----
__global__ __launch_bounds__(256) void cvt_q_i8(const float* __restrict__ x,
                                                s8* __restrict__ a, s8* __restrict__ b) {
  size_t i = ((size_t)blockIdx.x * 256 + threadIdx.x) * 8;
  float4 v0 = ((const float4*)(x + i))[0];
  float4 v1 = ((const float4*)(x + i))[1];
  float f[8] = {v0.x, v0.y, v0.z, v0.w, v1.x, v1.y, v1.z, v1.w};
  int q1[8], q2[8];
#pragma unroll
  for (int j = 0; j < 8; j++) qsplit(f[j], SQ, SQ_INV, SQ2_INV, q1[j], q2[j]);
  uint2 ua, ub;
  ua.x = pack4(q1[0], q1[1], q1[2], q1[3]); ua.y = pack4(q1[4], q1[5], q1[6], q1[7]);
  ub.x = pack4(q2[0], q2[1], q2[2], q2[3]); ub.y = pack4(q2[4], q2[5], q2[6], q2[7]);
  *(uint2*)(a + i) = ua;
  *(uint2*)(b + i) = ub;
}

// ---- K: one pass -> K1/K2 [t][d] + KT1/KT2 [d][t] int8 ----
__global__ __launch_bounds__(256) void cvt_k_i8(const float* __restrict__ K,
                                                s8* __restrict__ k1, s8* __restrict__ k2,
                                                s8* __restrict__ t1, s8* __restrict__ t2) {
  __shared__ uint32_t tile[64][33];  // low byte q1, next byte q2
  const int b = blockIdx.z;
  const int d0 = blockIdx.x * 32, t0 = blockIdx.y * 64;
  const int tid = threadIdx.x;
  const float* Kb = K + (size_t)b * 2048 * 1024;
  {
    const int t = tid >> 2, d8 = (tid & 3) * 8;
    const float* src = Kb + (size_t)(t0 + t) * 1024 + d0 + d8;
    float4 v0 = ((const float4*)src)[0];
    float4 v1 = ((const float4*)src)[1];
    float f[8] = {v0.x, v0.y, v0.z, v0.w, v1.x, v1.y, v1.z, v1.w};
    int q1[8], q2[8];
#pragma unroll
    for (int j = 0; j < 8; j++) {
      qsplit(f[j], SQ, SQ_INV, SQ2_INV, q1[j], q2[j]);
      tile[t][d8 + j] = ((uint32_t)(uint8_t)q1[j]) | ((uint32_t)(uint8_t)q2[j] << 8);
    }
    uint2 ua, ub;
    ua.x = pack4(q1[0], q1[1], q1[2], q1[3]); ua.y = pack4(q1[4], q1[5], q1[6], q1[7]);
    ub.x = pack4(q2[0], q2[1], q2[2], q2[3]); ub.y = pack4(q2[4], q2[5], q2[6], q2[7]);
    size_t off = (size_t)b * 2048 * 1024 + (size_t)(t0 + t) * 1024 + d0 + d8;
    *(uint2*)(k1 + off) = ua;
    *(uint2*)(k2 + off) = ub;
  }
  __syncthreads();
  {
    const int d = tid >> 3, tg = tid & 7;
    uint32_t v[8];
#pragma unroll
    for (int i = 0; i < 8; i++) v[i] = tile[tg * 8 + i][d];
    uint2 ua, ub;
    ua.x = pack4(v[0], v[1], v[2], v[3]); ua.y = pack4(v[4], v[5], v[6], v[7]);
    ub.x = pack4(v[0] >> 8, v[1] >> 8, v[2] >> 8, v[3] >> 8);
    ub.y = pack4(v[4] >> 8, v[5] >> 8, v[6] >> 8, v[7] >> 8);
    size_t off = (size_t)b * 1024 * 2048 + (size_t)(d0 + d) * 2048 + t0 + tg * 8;
    *(uint2*)(t1 + off) = ua;
    *(uint2*)(t2 + off) = ub;
  }
}

// ---- row softmax: E fp32 [rows][2048] -> P1,P2 int8 (P ~= (p1 + p2/128)/127) ----
__global__ __launch_bounds__(256) void softmax_i8(const float* __restrict__ E,
                                                  s8* __restrict__ P1, s8* __restrict__ P2) {
  const size_t row = blockIdx.x;
  const float* e = E + row * 2048;
  const int t = threadIdx.x;
  float4 a = ((const float4*)e)[t * 2];
  float4 b = ((const float4*)e)[t * 2 + 1];
  float f[8] = {a.x, a.y, a.z, a.w, b.x, b.y, b.z, b.w};
  float m = f[0];
#pragma unroll
  for (int j = 1; j < 8; j++) m = fmaxf(m, f[j]);
#pragma unroll
  for (int off = 32; off > 0; off >>= 1) m = fmaxf(m, __shfl_down(m, off));
  __shared__ float redm[4], reds[4];
  if ((t & 63) == 0) redm[t >> 6] = m;
  __syncthreads();
  m = fmaxf(fmaxf(redm[0], redm[1]), fmaxf(redm[2], redm[3]));
  float ex[8];
  float s = 0.f;
#pragma unroll
  for (int j = 0; j < 8; j++) { ex[j] = __expf(f[j] - m); s += ex[j]; }
#pragma unroll
  for (int off = 32; off > 0; off >>= 1) s += __shfl_down(s, off);
  if ((t & 63) == 0) reds[t >> 6] = s;
  __syncthreads();
  s = reds[0] + reds[1] + reds[2] + reds[3];
  float inv = 1.0f / s;
  int q1[8], q2[8];
#pragma unroll
  for (int j = 0; j < 8; j++)
    qsplit(ex[j] * inv, 1.0f / 127.0f, 127.0f, 16256.0f, q1[j], q2[j]);
  uint2 ua, ub;
  ua.x = pack4(q1[0], q1[1], q1[2], q1[3]); ua.y = pack4(q1[4], q1[5], q1[6], q1[7]);
  ub.x = pack4(q2[0], q2[1], q2[2], q2[3]); ub.y = pack4(q2[4], q2[5], q2[6], q2[7]);
  *(uint2*)(P1 + row * 2048 + t * 8) = ua;
  *(uint2*)(P2 + row * 2048 + t * 8) = ub;
}

// ---- unified dual-int8 GEMM: C = c1*(A1.B1^T) + c2*(A1.B2^T + A2.B1^T) ----
// 128x128 tile, BK=64, 4 waves, wave tile 64x64. Counted-vmcnt double-buffer
// (round-3 pipeline). NEW this round:
//  * XCD-chunked block swizzle: flat id remapped so each XCD owns an 8-wide
//    column band x all rows (gemm1) / a (z, y-half) chunk (gemm2). B-panels
//    (4 MB) become L2-resident per XCD; A-panels shared by 8 consecutive
//    co-resident blocks. Cuts over-fetch (74/141 MB) and load latency, which
//    the 1-deep prefetch pipeline is directly exposed to.
//  * s_setprio(1) around the MFMA cluster: 2 independent blocks/CU at skewed
//    phases -> scheduler favors the compute-phase wave.
// Requires gridDim.x % 8 == 0 (or ==8) and nwg % 8 == 0: holds (16,16,4)/(8,16,4).
__global__ __launch_bounds__(256, 2) void gemm_i8(
    const s8* __restrict__ A0, const s8* __restrict__ A1,
    const s8* __restrict__ B0, const s8* __restrict__ B1,
    float* __restrict__ C, int Kdim, int ldc, long sA, long sB, long sC,
    float c1, float c2) {
  __shared__ char lds[2][32768];  // per buf: A1@0, A2@8192, B1@16384, B2@24576
  const int tid = threadIdx.x;
  const int w = tid >> 6, l = tid & 63;

  // ---- XCD-chunked swizzle ----
  const int gx = gridDim.x, gy = gridDim.y;
  const int nwg = gx * gy * gridDim.z;
  const int f = (blockIdx.z * gy + blockIdx.y) * gx + blockIdx.x;
  const int cpx = nwg >> 3;                  // blocks per XCD (nwg % 8 == 0)
  const int swz = (f & 7) * cpx + (f >> 3);  // XCD (f&7) owns [c*cpx,(c+1)*cpx)
  // decode swz: x fastest within 8-wide bands, then y, then band index
  const int bandsz = 8 * gy;
  const int band = swz / bandsz, r = swz % bandsz;
  const int nbx = gx >> 3;                   // bands per grid row
  const int bx = (band % nbx) * 8 + (r & 7);
  const int by = r >> 3;
  const int bz = band / nbx;

  const int rowA = by * 128, rowB = bx * 128;
  const s8* bases[4] = {A0 + bz * sA, A1 + bz * sA, B0 + bz * sB, B1 + bz * sB};
  const int rbase[4] = {rowA, rowA, rowB, rowB};
  const s8* gp[8];
  uint32_t lpo[8];
#pragma unroll
  for (int i = 0; i < 8; i++) {
    int gc = w * 8 + i;                 // 32 chunks of 1KB over 4 waves
    int buf = gc >> 3, c = gc & 7;
    int row = c * 16 + (l >> 2);
    int q = (l & 3) ^ ((row >> 1) & 3);
    gp[i] = bases[buf] + (size_t)(rbase[buf] + row) * Kdim + q * 16;
    lpo[i] = (uint32_t)(uintptr_t)(&lds[0][0] + buf * 8192 + c * 1024 + l * 16);
  }
  i32x4 acc1[4][4], acc2[4][4];
  const i32x4 zero = {0, 0, 0, 0};
#pragma unroll
  for (int mt = 0; mt < 4; mt++)
#pragma unroll
    for (int nt = 0; nt < 4; nt++) { acc1[mt][nt] = zero; acc2[mt][nt] = zero; }

  const int wm = w & 1, wn = w >> 1, q4 = l >> 4, rl = l & 15;

  // prologue: stage tile 0 into buffer 0
#pragma unroll
  for (int i = 0; i < 8; i++) { gload_lds16(gp[i], lpo[i]); gp[i] += 64; }

  int cur = 0;
  for (int k0 = 0; k0 < Kdim; k0 += 64) {
    // barrier A: all waves done reading buf[cur^1] before its overwrite begins
    __builtin_amdgcn_s_barrier();
    if (k0 + 64 < Kdim) {
      const uint32_t nb = (uint32_t)(cur ^ 1) * 32768u;
#pragma unroll
      for (int i = 0; i < 8; i++) { gload_lds16(gp[i], lpo[i] + nb); gp[i] += 64; }
      // wait own tile-t loads only (8 newest = t+1's stay in flight)
      asm volatile("s_waitcnt vmcnt(8)" ::: "memory");
    } else {
      asm volatile("s_waitcnt vmcnt(0)" ::: "memory");
    }
    __builtin_amdgcn_sched_barrier(0);
    __builtin_amdgcn_s_barrier();  // barrier B: buf[cur] fully staged for all
    const char* L = &lds[cur][0];
    i32x4 af0[4], af1[4];
#pragma unroll
    for (int mt = 0; mt < 4; mt++) {
      int row = wm * 64 + mt * 16 + rl;
      int off = row * 64 + ((q4 ^ ((row >> 1) & 3)) << 4);
      af0[mt] = *(const i32x4*)(L + off);
      af1[mt] = *(const i32x4*)(L + 8192 + off);
    }
    __builtin_amdgcn_s_setprio(1);
#pragma unroll
    for (int nt = 0; nt < 4; nt++) {
      int row = wn * 64 + nt * 16 + rl;
      int off = row * 64 + ((q4 ^ ((row >> 1) & 3)) << 4);
      i32x4 bf0 = *(const i32x4*)(L + 16384 + off);
      i32x4 bf1 = *(const i32x4*)(L + 24576 + off);
#pragma unroll
      for (int mt = 0; mt < 4; mt++) {
        acc1[mt][nt] = __builtin_amdgcn_mfma_i32_16x16x64_i8(af0[mt], bf0, acc1[mt][nt], 0, 0, 0);
        acc2[mt][nt] = __builtin_amdgcn_mfma_i32_16x16x64_i8(af0[mt], bf1, acc2[mt][nt], 0, 0, 0);
        acc2[mt][nt] = __builtin_amdgcn_mfma_i32_16x16x64_i8(af1[mt], bf0, acc2[mt][nt], 0, 0, 0);
      }
    }
    __builtin_amdgcn_s_setprio(0);
    cur ^= 1;
  }
  float* Cb = C + (size_t)bz * sC + (size_t)rowA * ldc + rowB;
#pragma unroll
  for (int mt = 0; mt < 4; mt++)
#pragma unroll
    for (int nt = 0; nt < 4; nt++)
#pragma unroll
      for (int r2 = 0; r2 < 4; r2++)
        Cb[(size_t)(wm * 64 + mt * 16 + q4 * 4 + r2) * ldc + (wn * 64 + nt * 16 + rl)] =
            c1 * (float)acc1[mt][nt][r2] + c2 * (float)acc2[mt][nt][r2];
}

extern "C" void kernel_launch(void* const* d_in, const int* in_sizes, int n_in,
                              void* d_out, int out_size, void* d_ws, size_t ws_size,
                              hipStream_t stream) {
  (void)in_sizes; (void)n_in; (void)out_size;
  const float* Q = (const float*)d_in[0];
  const float* K = (const float*)d_in[1];
  float* O = (float*)d_out;
  const int Btot = 8, Tq = 2048, Tk = 2048, D = 1024;
  // ws per batch: Q1,Q2,K1,K2,KT1,KT2 int8 (2MB each) + E fp32 16MB + P1,P2 int8 (4MB each) = 36MB
  const size_t perb = 36ull << 20;
  int NB = 8;
  while (NB > 1 && (size_t)NB * perb > ws_size) NB >>= 1;

  char* p = (char*)d_ws;
  const size_t qd = (size_t)NB * Tq * D;
  const size_t kd = (size_t)NB * Tk * D;
  const size_t ee = (size_t)NB * Tq * Tk;
  s8* Q1 = (s8*)p; p += qd;
  s8* Q2 = (s8*)p; p += qd;
  s8* K1 = (s8*)p; p += kd;
  s8* K2 = (s8*)p; p += kd;
  s8* KT1 = (s8*)p; p += kd;
  s8* KT2 = (s8*)p; p += kd;
  float* E = (float*)p; p += ee * 4;
  s8* P1 = (s8*)p; p += ee;
  s8* P2 = (s8*)p; p += ee;

  const float g1c1 = 64.0f / 16129.0f, g1c2 = g1c1 * (1.0f / 128.0f);
  const float g2c1 = 8.0f / 16129.0f, g2c2 = g2c1 * (1.0f / 128.0f);

  for (int c = 0; c < Btot / NB; c++) {
    const float* Qc = Q + (size_t)c * qd;
    const float* Kc = K + (size_t)c * kd;
    float* Oc = O + (size_t)c * qd;
    cvt_q_i8<<<dim3(NB * 1024), 256, 0, stream>>>(Qc, Q1, Q2);
    cvt_k_i8<<<dim3(32, 32, NB), 256, 0, stream>>>(Kc, K1, K2, KT1, KT2);
    gemm_i8<<<dim3(16, 16, NB), 256, 0, stream>>>(
        Q1, Q2, K1, K2, E, 1024, 2048, (long)Tq * D, (long)Tk * D, (long)Tq * Tk,
        g1c1, g1c2);
    softmax_i8<<<dim3(NB * Tq), 256, 0, stream>>>(E, P1, P2);
    gemm_i8<<<dim3(8, 16, NB), 256, 0, stream>>>(
        P1, P2, KT1, KT2, Oc, 2048, 1024, (long)Tq * Tk, (long)D * Tk, (long)Tq * D,
        g2c1, g2c2);
  }
}

// Round 6
// 386.051 us; speedup vs baseline: 1.4583x; 1.0474x over previous
//
#include <hip/hip_runtime.h>
#include <stdint.h>

typedef int i32x4 __attribute__((ext_vector_type(4)));
typedef int8_t s8;

// ---- async global->LDS, 16B per lane ----
__device__ __forceinline__ void gload_lds16(const void* g, uint32_t lds_addr) {
  __builtin_amdgcn_global_load_lds(
      (const __attribute__((address_space(1))) void*)(uintptr_t)g,
      (__attribute__((address_space(3))) void*)(uintptr_t)lds_addr,
      16, 0, 0);
}

// ---- 2-level int8 split: x ~= s*(q1 + q2/128), |err| <= s/512 ----
__device__ __forceinline__ void qsplit(float x, float s, float sinv, float s2inv,
                                       int& q1, int& q2) {
  float a = rintf(x * sinv);
  a = fminf(fmaxf(a, -127.f), 127.f);
  float r = fmaf(a, -s, x);
  float b = fminf(fmaxf(rintf(r * s2inv), -127.f), 127.f);
  q1 = (int)a; q2 = (int)b;
}
__device__ __forceinline__ uint32_t pack4(int b0, int b1, int b2, int b3) {
  return ((uint32_t)(uint8_t)b0) | ((uint32_t)(uint8_t)b1 << 8) |
         ((uint32_t)(uint8_t)b2 << 16) | ((uint32_t)(uint8_t)b3 << 24);
}

#define SQ (8.0f / 127.0f)
#define SQ_INV 15.875f
#define SQ2_INV 2032.0f

// ---- Q: fp32 -> q1,q2 int8; 8 elems/thread ----
__global__ __launch_bounds__(256) void cvt_q_i8(const float* __restrict__ x,
                                                s8* __restrict__ a, s8* __restrict__ b) {
  size_t i = ((size_t)blockIdx.x * 256 + threadIdx.x) * 8;
  float4 v0 = ((const float4*)(x + i))[0];
  float4 v1 = ((const float4*)(x + i))[1];
  float f[8] = {v0.x, v0.y, v0.z, v0.w, v1.x, v1.y, v1.z, v1.w};
  int q1[8], q2[8];
#pragma unroll
  for (int j = 0; j < 8; j++) qsplit(f[j], SQ, SQ_INV, SQ2_INV, q1[j], q2[j]);
  uint2 ua, ub;
  ua.x = pack4(q1[0], q1[1], q1[2], q1[3]); ua.y = pack4(q1[4], q1[5], q1[6], q1[7]);
  ub.x = pack4(q2[0], q2[1], q2[2], q2[3]); ub.y = pack4(q2[4], q2[5], q2[6], q2[7]);
  *(uint2*)(a + i) = ua;
  *(uint2*)(b + i) = ub;
}

// ---- K: one pass -> K1/K2 [t][d] + KT1/KT2 [d][t] int8 ----
__global__ __launch_bounds__(256) void cvt_k_i8(const float* __restrict__ K,
                                                s8* __restrict__ k1, s8* __restrict__ k2,
                                                s8* __restrict__ t1, s8* __restrict__ t2) {
  __shared__ uint32_t tile[64][33];  // low byte q1, next byte q2
  const int b = blockIdx.z;
  const int d0 = blockIdx.x * 32, t0 = blockIdx.y * 64;
  const int tid = threadIdx.x;
  const float* Kb = K + (size_t)b * 2048 * 1024;
  {
    const int t = tid >> 2, d8 = (tid & 3) * 8;
    const float* src = Kb + (size_t)(t0 + t) * 1024 + d0 + d8;
    float4 v0 = ((const float4*)src)[0];
    float4 v1 = ((const float4*)src)[1];
    float f[8] = {v0.x, v0.y, v0.z, v0.w, v1.x, v1.y, v1.z, v1.w};
    int q1[8], q2[8];
#pragma unroll
    for (int j = 0; j < 8; j++) {
      qsplit(f[j], SQ, SQ_INV, SQ2_INV, q1[j], q2[j]);
      tile[t][d8 + j] = ((uint32_t)(uint8_t)q1[j]) | ((uint32_t)(uint8_t)q2[j] << 8);
    }
    uint2 ua, ub;
    ua.x = pack4(q1[0], q1[1], q1[2], q1[3]); ua.y = pack4(q1[4], q1[5], q1[6], q1[7]);
    ub.x = pack4(q2[0], q2[1], q2[2], q2[3]); ub.y = pack4(q2[4], q2[5], q2[6], q2[7]);
    size_t off = (size_t)b * 2048 * 1024 + (size_t)(t0 + t) * 1024 + d0 + d8;
    *(uint2*)(k1 + off) = ua;
    *(uint2*)(k2 + off) = ub;
  }
  __syncthreads();
  {
    const int d = tid >> 3, tg = tid & 7;
    uint32_t v[8];
#pragma unroll
    for (int i = 0; i < 8; i++) v[i] = tile[tg * 8 + i][d];
    uint2 ua, ub;
    ua.x = pack4(v[0], v[1], v[2], v[3]); ua.y = pack4(v[4], v[5], v[6], v[7]);
    ub.x = pack4(v[0] >> 8, v[1] >> 8, v[2] >> 8, v[3] >> 8);
    ub.y = pack4(v[4] >> 8, v[5] >> 8, v[6] >> 8, v[7] >> 8);
    size_t off = (size_t)b * 1024 * 2048 + (size_t)(d0 + d) * 2048 + t0 + tg * 8;
    *(uint2*)(t1 + off) = ua;
    *(uint2*)(t2 + off) = ub;
  }
}

// ---- row softmax: E fp32 [rows][2048] -> P1,P2 int8 (P ~= (p1 + p2/128)/127) ----
__global__ __launch_bounds__(256) void softmax_i8(const float* __restrict__ E,
                                                  s8* __restrict__ P1, s8* __restrict__ P2) {
  const size_t row = blockIdx.x;
  const float* e = E + row * 2048;
  const int t = threadIdx.x;
  float4 a = ((const float4*)e)[t * 2];
  float4 b = ((const float4*)e)[t * 2 + 1];
  float f[8] = {a.x, a.y, a.z, a.w, b.x, b.y, b.z, b.w};
  float m = f[0];
#pragma unroll
  for (int j = 1; j < 8; j++) m = fmaxf(m, f[j]);
#pragma unroll
  for (int off = 32; off > 0; off >>= 1) m = fmaxf(m, __shfl_down(m, off));
  __shared__ float redm[4], reds[4];
  if ((t & 63) == 0) redm[t >> 6] = m;
  __syncthreads();
  m = fmaxf(fmaxf(redm[0], redm[1]), fmaxf(redm[2], redm[3]));
  float ex[8];
  float s = 0.f;
#pragma unroll
  for (int j = 0; j < 8; j++) { ex[j] = __expf(f[j] - m); s += ex[j]; }
#pragma unroll
  for (int off = 32; off > 0; off >>= 1) s += __shfl_down(s, off);
  if ((t & 63) == 0) reds[t >> 6] = s;
  __syncthreads();
  s = reds[0] + reds[1] + reds[2] + reds[3];
  float inv = 1.0f / s;
  int q1[8], q2[8];
#pragma unroll
  for (int j = 0; j < 8; j++)
    qsplit(ex[j] * inv, 1.0f / 127.0f, 127.0f, 16256.0f, q1[j], q2[j]);
  uint2 ua, ub;
  ua.x = pack4(q1[0], q1[1], q1[2], q1[3]); ua.y = pack4(q1[4], q1[5], q1[6], q1[7]);
  ub.x = pack4(q2[0], q2[1], q2[2], q2[3]); ub.y = pack4(q2[4], q2[5], q2[6], q2[7]);
  *(uint2*)(P1 + row * 2048 + t * 8) = ua;
  *(uint2*)(P2 + row * 2048 + t * 8) = ub;
}

// ---- unified dual-int8 GEMM: C = c1*(A1.B1^T) + c2*(A1.B2^T + A2.B1^T) ----
// 128x128 tile, BK=64, 4 waves, wave tile 64x64. Round-5 base (XCD swizzle:
// FETCH == input size; counted-vmcnt dbuf) + NEW: 4-phase interleave per K-iter
// (T3). 1-phase had DS pipe (~2260cy/CU/slot) and MFMA pipe (~1960cy/SIMD)
// each <50% of the 4190cy slot but serialized (burst-read then burst-MFMA).
// Phases: P0 {read all A-frags + bf[0], stage 2, lgkm(0), 12 MFMA},
// P1-P3 {read bf[p], stage 2 (P3:0), lgkm(0), 12 MFMA}, barrier between.
// Each phase's reads drain under the neighbor phase's MFMA cluster.
// vmcnt: 2 loads at iter head -> vmcnt(2) waits exactly tile-t's 8.
__global__ __launch_bounds__(256, 2) void gemm_i8(
    const s8* __restrict__ A0, const s8* __restrict__ A1,
    const s8* __restrict__ B0, const s8* __restrict__ B1,
    float* __restrict__ C, int Kdim, int ldc, long sA, long sB, long sC,
    float c1, float c2) {
  __shared__ char lds[2][32768];  // per buf: A1@0, A2@8192, B1@16384, B2@24576
  const int tid = threadIdx.x;
  const int w = tid >> 6, l = tid & 63;

  // ---- XCD-chunked swizzle (round-5, verified: FETCH = input size) ----
  const int gx = gridDim.x, gy = gridDim.y;
  const int nwg = gx * gy * gridDim.z;
  const int f = (blockIdx.z * gy + blockIdx.y) * gx + blockIdx.x;
  const int cpx = nwg >> 3;                  // blocks per XCD (nwg % 8 == 0)
  const int swz = (f & 7) * cpx + (f >> 3);  // XCD (f&7) owns [c*cpx,(c+1)*cpx)
  const int bandsz = 8 * gy;
  const int band = swz / bandsz, r = swz % bandsz;
  const int nbx = gx >> 3;                   // bands per grid row
  const int bx = (band % nbx) * 8 + (r & 7);
  const int by = r >> 3;
  const int bz = band / nbx;

  const int rowA = by * 128, rowB = bx * 128;
  const s8* bases[4] = {A0 + bz * sA, A1 + bz * sA, B0 + bz * sB, B1 + bz * sB};
  const int rbase[4] = {rowA, rowA, rowB, rowB};
  const s8* gp[8];
  uint32_t lpo[8];
#pragma unroll
  for (int i = 0; i < 8; i++) {
    int gc = w * 8 + i;                 // 32 chunks of 1KB over 4 waves
    int buf = gc >> 3, c = gc & 7;
    int row = c * 16 + (l >> 2);
    int q = (l & 3) ^ ((row >> 1) & 3);
    gp[i] = bases[buf] + (size_t)(rbase[buf] + row) * Kdim + q * 16;
    lpo[i] = (uint32_t)(uintptr_t)(&lds[0][0] + buf * 8192 + c * 1024 + l * 16);
  }
  i32x4 acc1[4][4], acc2[4][4];
  const i32x4 zero = {0, 0, 0, 0};
#pragma unroll
  for (int mt = 0; mt < 4; mt++)
#pragma unroll
    for (int nt = 0; nt < 4; nt++) { acc1[mt][nt] = zero; acc2[mt][nt] = zero; }

  const int wm = w & 1, wn = w >> 1, q4 = l >> 4, rl = l & 15;

  // prologue: stage tile 0 into buffer 0
#pragma unroll
  for (int i = 0; i < 8; i++) { gload_lds16(gp[i], lpo[i]); gp[i] += 64; }

#define STAGE2(i0, i1)                                         \
  do {                                                         \
    gload_lds16(gp[i0], lpo[i0] + nb); gp[i0] += 64;           \
    gload_lds16(gp[i1], lpo[i1] + nb); gp[i1] += 64;           \
  } while (0)

#define GPHASE(p, STAGE_STMT)                                                  \
  {                                                                            \
    int row_ = wn * 64 + (p) * 16 + rl;                                        \
    int off_ = row_ * 64 + ((q4 ^ ((row_ >> 1) & 3)) << 4);                    \
    i32x4 bf0 = *(const i32x4*)(L + 16384 + off_);                             \
    i32x4 bf1 = *(const i32x4*)(L + 24576 + off_);                             \
    if (pf) { STAGE_STMT; }                                                    \
    asm volatile("s_waitcnt lgkmcnt(0)" ::: "memory");                         \
    __builtin_amdgcn_sched_barrier(0);                                         \
    __builtin_amdgcn_s_setprio(1);                                             \
    _Pragma("unroll")                                                          \
    for (int mt = 0; mt < 4; mt++) {                                           \
      acc1[mt][p] = __builtin_amdgcn_mfma_i32_16x16x64_i8(af0[mt], bf0, acc1[mt][p], 0, 0, 0); \
      acc2[mt][p] = __builtin_amdgcn_mfma_i32_16x16x64_i8(af0[mt], bf1, acc2[mt][p], 0, 0, 0); \
      acc2[mt][p] = __builtin_amdgcn_mfma_i32_16x16x64_i8(af1[mt], bf0, acc2[mt][p], 0, 0, 0); \
    }                                                                          \
    __builtin_amdgcn_s_setprio(0);                                             \
  }

  int cur = 0;
  for (int k0 = 0; k0 < Kdim; k0 += 64) {
    const bool pf = (k0 + 64 < Kdim);
    const uint32_t nb = (uint32_t)(cur ^ 1) * 32768u;
    // barrier A: all waves done reading buf[cur^1] before its overwrite begins
    __builtin_amdgcn_s_barrier();
    if (pf) {
      STAGE2(0, 1);
      // wait own tile-t loads only (2 newest = t+1's stay in flight)
      asm volatile("s_waitcnt vmcnt(2)" ::: "memory");
    } else {
      asm volatile("s_waitcnt vmcnt(0)" ::: "memory");
    }
    __builtin_amdgcn_sched_barrier(0);
    __builtin_amdgcn_s_barrier();  // barrier B: buf[cur] fully staged for all
    __builtin_amdgcn_sched_barrier(0);
    const char* L = &lds[cur][0];
    // P0: read all A fragments + bf[0]; stage 2; 12 MFMA (nt=0)
    i32x4 af0[4], af1[4];
#pragma unroll
    for (int mt = 0; mt < 4; mt++) {
      int row = wm * 64 + mt * 16 + rl;
      int off = row * 64 + ((q4 ^ ((row >> 1) & 3)) << 4);
      af0[mt] = *(const i32x4*)(L + off);
      af1[mt] = *(const i32x4*)(L + 8192 + off);
    }
    GPHASE(0, STAGE2(2, 3));
    __builtin_amdgcn_s_barrier();
    GPHASE(1, STAGE2(4, 5));
    __builtin_amdgcn_s_barrier();
    GPHASE(2, STAGE2(6, 7));
    __builtin_amdgcn_s_barrier();
    GPHASE(3, ((void)0));
    cur ^= 1;
  }
#undef GPHASE
#undef STAGE2
  float* Cb = C + (size_t)bz * sC + (size_t)rowA * ldc + rowB;
#pragma unroll
  for (int mt = 0; mt < 4; mt++)
#pragma unroll
    for (int nt = 0; nt < 4; nt++)
#pragma unroll
      for (int r2 = 0; r2 < 4; r2++)
        Cb[(size_t)(wm * 64 + mt * 16 + q4 * 4 + r2) * ldc + (wn * 64 + nt * 16 + rl)] =
            c1 * (float)acc1[mt][nt][r2] + c2 * (float)acc2[mt][nt][r2];
}

extern "C" void kernel_launch(void* const* d_in, const int* in_sizes, int n_in,
                              void* d_out, int out_size, void* d_ws, size_t ws_size,
                              hipStream_t stream) {
  (void)in_sizes; (void)n_in; (void)out_size;
  const float* Q = (const float*)d_in[0];
  const float* K = (const float*)d_in[1];
  float* O = (float*)d_out;
  const int Btot = 8, Tq = 2048, Tk = 2048, D = 1024;
  // ws per batch: Q1,Q2,K1,K2,KT1,KT2 int8 (2MB each) + E fp32 16MB + P1,P2 int8 (4MB each) = 36MB
  const size_t perb = 36ull << 20;
  int NB = 8;
  while (NB > 1 && (size_t)NB * perb > ws_size) NB >>= 1;

  char* p = (char*)d_ws;
  const size_t qd = (size_t)NB * Tq * D;
  const size_t kd = (size_t)NB * Tk * D;
  const size_t ee = (size_t)NB * Tq * Tk;
  s8* Q1 = (s8*)p; p += qd;
  s8* Q2 = (s8*)p; p += qd;
  s8* K1 = (s8*)p; p += kd;
  s8* K2 = (s8*)p; p += kd;
  s8* KT1 = (s8*)p; p += kd;
  s8* KT2 = (s8*)p; p += kd;
  float* E = (float*)p; p += ee * 4;
  s8* P1 = (s8*)p; p += ee;
  s8* P2 = (s8*)p; p += ee;

  const float g1c1 = 64.0f / 16129.0f, g1c2 = g1c1 * (1.0f / 128.0f);
  const float g2c1 = 8.0f / 16129.0f, g2c2 = g2c1 * (1.0f / 128.0f);

  for (int c = 0; c < Btot / NB; c++) {
    const float* Qc = Q + (size_t)c * qd;
    const float* Kc = K + (size_t)c * kd;
    float* Oc = O + (size_t)c * qd;
    cvt_q_i8<<<dim3(NB * 1024), 256, 0, stream>>>(Qc, Q1, Q2);
    cvt_k_i8<<<dim3(32, 32, NB), 256, 0, stream>>>(Kc, K1, K2, KT1, KT2);
    gemm_i8<<<dim3(16, 16, NB), 256, 0, stream>>>(
        Q1, Q2, K1, K2, E, 1024, 2048, (long)Tq * D, (long)Tk * D, (long)Tq * Tk,
        g1c1, g1c2);
    softmax_i8<<<dim3(NB * Tq), 256, 0, stream>>>(E, P1, P2);
    gemm_i8<<<dim3(8, 16, NB), 256, 0, stream>>>(
        P1, P2, KT1, KT2, Oc, 2048, 1024, (long)Tq * Tk, (long)D * Tk, (long)Tq * D,
        g2c1, g2c2);
  }
}